// Round 2
// baseline (130.073 us; speedup 1.0000x reference)
//
#include <hip/hip_runtime.h>
#include <math.h>

#define N_TOK 8192
#define DIM   1024
#define NE    8
#define NR    16
#define NO    3072
#define OUT_ELEMS (N_TOK * NO)   // 25165824

__device__ __forceinline__ float softplusf(float z) {
  return z > 0.f ? z + log1pf(expf(-z)) : log1pf(expf(z));
}
__device__ __forceinline__ float ncdf(float z) {
  return 0.5f * erfcf(-z * 0.70710678118654752f);
}

#define FMA4(A, S, W) { (A).x = fmaf((S),(W).x,(A).x); (A).y = fmaf((S),(W).y,(A).y); \
                        (A).z = fmaf((S),(W).z,(A).z); (A).w = fmaf((S),(W).w,(A).w); }
#define DOT4ACC(ACC, X, W) ACC = fmaf((X).x,(W).x, fmaf((X).y,(W).y, fmaf((X).z,(W).z, fmaf((X).w,(W).w,(ACC)))))

// ---------------------------------------------------------------------------
// Kernel T: transpose [w_gate | w_noise] (each [1024][8]) -> wT[16][1024].
// block o = 0..15; coalesced writes, strided reads (64 KB total, trivial).
// ---------------------------------------------------------------------------
__global__ __launch_bounds__(256) void kT(const float* __restrict__ wg,
    const float* __restrict__ wn, float* __restrict__ wT) {
  int o = blockIdx.x;
  const float* src = (o < 8 ? wg : wn);
  int col = o & 7;
  int t = threadIdx.x;
  #pragma unroll
  for (int k = 0; k < 4; ++k) {
    int d = t + (k << 8);
    wT[o * DIM + d] = src[d * NE + col];
  }
}

// ---------------------------------------------------------------------------
// Kernel A: gating GEMV. 16 tokens/block; wave = 4 tokens x 16 d-lanes.
// Each lane: 16 scalar accs (all outputs), coalesced float4 loads of x and wT.
// Then top-2, expert id, prob, block partials (epilogue on threads 0..15).
// ---------------------------------------------------------------------------
__global__ __launch_bounds__(256) void kA(const float* __restrict__ x,
    const float* __restrict__ wT, const float* __restrict__ nz,
    int* __restrict__ eid, float* __restrict__ part) {
  __shared__ float lg_lds[16][20];
  int t = threadIdx.x;
  int n0 = blockIdx.x << 4;
  int wid = t >> 6, lane = t & 63;
  int tokw = lane >> 4, dsub = lane & 15;
  int tok = (wid << 2) + tokw;                    // 0..15 within block
  const float* xr = x + (size_t)(n0 + tok) * DIM + (dsub << 2);
  const float* wr = wT + (dsub << 2);
  float acc[16];
  #pragma unroll
  for (int o = 0; o < 16; ++o) acc[o] = 0.f;
  #pragma unroll 4
  for (int m = 0; m < 16; ++m) {
    float4 xv = *(const float4*)(xr + (m << 6));
    #pragma unroll
    for (int o = 0; o < 16; ++o) {
      float4 wv = *(const float4*)(wr + o * DIM + (m << 6));
      DOT4ACC(acc[o], xv, wv);
    }
  }
  #pragma unroll
  for (int off = 1; off <= 8; off <<= 1) {
    #pragma unroll
    for (int o = 0; o < 16; ++o) acc[o] += __shfl_xor(acc[o], off);
  }
  if (dsub == 0) {
    #pragma unroll
    for (int o = 0; o < 16; o += 4)
      *(float4*)&lg_lds[tok][o] = make_float4(acc[o], acc[o+1], acc[o+2], acc[o+3]);
  }
  __syncthreads();
  if (t < 16) {
    int n = n0 + t;
    float cl[8], st[8], lg[8];
    #pragma unroll
    for (int e = 0; e < 8; ++e) cl[e] = lg_lds[t][e];
    #pragma unroll
    for (int e = 0; e < 8; ++e) {
      st[e] = softplusf(lg_lds[t][8 + e]) + 0.01f;
      lg[e] = fmaf(nz[(size_t)n * NE + e], st[e], cl[e]);
    }
    float m1 = -1e30f, m2 = -1e30f; int idx = 0;
    #pragma unroll
    for (int e = 0; e < 8; ++e) {
      float v = lg[e];
      if (v > m1)      { m2 = m1; m1 = v; idx = e; }
      else if (v > m2) { m2 = v; }
    }
    eid[n] = idx;
    float pr[8], cw[8];
    #pragma unroll
    for (int e = 0; e < 8; ++e) {
      float thr = (lg[e] > m2) ? m2 : m1;
      pr[e] = ncdf((cl[e] - thr) / st[e]);
    }
    #pragma unroll
    for (int e = 0; e < 8; ++e) cw[e] = (float)__popcll(__ballot(idx == e));
    #pragma unroll
    for (int e = 0; e < 8; ++e) {
      #pragma unroll
      for (int off = 1; off <= 8; off <<= 1) pr[e] += __shfl_xor(pr[e], off);
    }
    if (t == 0) {
      #pragma unroll
      for (int e = 0; e < 8; ++e) {
        part[blockIdx.x * 16 + e]     = cw[e];
        part[blockIdx.x * 16 + 8 + e] = pr[e];
      }
    }
  }
}

// ---------------------------------------------------------------------------
// Kernel B: reduce 512x16 partials -> importance[8], load[8] into d_out tail;
// also counts (int) and zero fill counters.
// ---------------------------------------------------------------------------
__global__ __launch_bounds__(256) void kB(const float* __restrict__ part,
    float* __restrict__ outIL, int* __restrict__ counts, int* __restrict__ fill) {
  __shared__ float red[16][16];
  int t = threadIdx.x;
  int s = t & 15, g = t >> 4;
  float sum = 0.f;
  for (int j = 0; j < 32; ++j) sum += part[(g + 16 * j) * 16 + s];
  red[g][s] = sum;
  __syncthreads();
  if (t < 16) {
    float tot = 0.f;
    #pragma unroll
    for (int gg = 0; gg < 16; ++gg) tot += red[gg][t];
    outIL[t] = tot;                       // [0..7] importance, [8..15] load
    if (t < 8) { counts[t] = (int)(tot + 0.5f); fill[t] = 0; }
  }
}

// ---------------------------------------------------------------------------
// Kernel C: bucket tokens by expert (two-level: LDS hist + 8 global atomics).
// ---------------------------------------------------------------------------
__global__ __launch_bounds__(256) void kC(const int* __restrict__ eid,
    const int* __restrict__ counts, int* __restrict__ fill, int* __restrict__ bucket) {
  __shared__ int lcnt[8], lbase[8];
  int t = threadIdx.x;
  if (t < 8) lcnt[t] = 0;
  __syncthreads();
  int n = blockIdx.x * 256 + t;
  int e = eid[n];
  int rank = atomicAdd(&lcnt[e], 1);
  __syncthreads();
  if (t < 8) lbase[t] = atomicAdd(&fill[t], lcnt[t]);
  __syncthreads();
  int off = 0;
  #pragma unroll
  for (int i = 0; i < 8; ++i) if (i < e) off += counts[i];
  bucket[off + lbase[e] + rank] = n;
}

// ---------------------------------------------------------------------------
// Kernel D: h_sorted[p] = lora_a[e] @ x[bucket[p]].  16 tokens/tile.
// Wave = 4 tokens x 16 d-lanes; lane holds all 16 r-accs; coalesced loads.
// lora_a is [E][R][D] row-major in d -> no transpose needed.
// ---------------------------------------------------------------------------
__global__ __launch_bounds__(256) void kD(const float* __restrict__ x,
    const float* __restrict__ la, const int* __restrict__ counts,
    const int* __restrict__ bucket, float* __restrict__ h) {
  __shared__ int toks[16];
  int tile = blockIdx.x;
  int e = -1, jt = 0, off = 0;
  { int tot = 0, o = 0;
    #pragma unroll
    for (int i = 0; i < 8; ++i) {
      int c = counts[i]; int nt = (c + 15) >> 4;
      if (e < 0 && tile < tot + nt) { e = i; jt = tile - tot; off = o; }
      tot += nt; o += c;
    } }
  if (e < 0) return;
  int cnt = counts[e];
  int p0 = off + (jt << 4);
  int valid = min(16, cnt - (jt << 4));
  int t = threadIdx.x;
  if (t < 16) toks[t] = bucket[p0 + min(t, valid - 1)];
  __syncthreads();
  int wid = t >> 6, lane = t & 63;
  int tokw = lane >> 4, dsub = lane & 15;
  int tok = (wid << 2) + tokw;                    // 0..15
  const float* xr = x + (size_t)toks[tok] * DIM + (dsub << 2);
  const float* ar = la + (size_t)e * NR * DIM + (dsub << 2);
  float acc[16];
  #pragma unroll
  for (int r = 0; r < 16; ++r) acc[r] = 0.f;
  #pragma unroll 4
  for (int m = 0; m < 16; ++m) {
    float4 xv = *(const float4*)(xr + (m << 6));
    #pragma unroll
    for (int r = 0; r < 16; ++r) {
      float4 av = *(const float4*)(ar + r * DIM + (m << 6));
      DOT4ACC(acc[r], xv, av);
    }
  }
  #pragma unroll
  for (int off2 = 1; off2 <= 8; off2 <<= 1) {
    #pragma unroll
    for (int r = 0; r < 16; ++r) acc[r] += __shfl_xor(acc[r], off2);
  }
  if (dsub == 0 && tok < valid) {
    float* hp = h + (size_t)(p0 + tok) * NR;
    #pragma unroll
    for (int r = 0; r < 16; r += 4)
      *(float4*)(hp + r) = make_float4(acc[r], acc[r+1], acc[r+2], acc[r+3]);
  }
}

// ---------------------------------------------------------------------------
// Kernel E: out[n] = lora_b[e] @ h. Tiles: 64 tokens x 256 outs.
// threads = og(32) x tokg(8); per-thread 8 tok x 8 outs (4 lo + 4 hi).
// ---------------------------------------------------------------------------
__global__ __launch_bounds__(256) void kE(const float* __restrict__ h,
    const float* __restrict__ lb, const int* __restrict__ counts,
    const int* __restrict__ bucket, float* __restrict__ out) {
  __shared__ float bt[16][260];
  __shared__ float ht[16][64];
  __shared__ int toks[64];
  int tile = blockIdx.y;
  int e = -1, jt = 0, off = 0;
  { int tot = 0, o = 0;
    #pragma unroll
    for (int i = 0; i < 8; ++i) {
      int c = counts[i]; int nt = (c + 63) >> 6;
      if (e < 0 && tile < tot + nt) { e = i; jt = tile - tot; off = o; }
      tot += nt; o += c;
    } }
  if (e < 0) return;
  int cnt = counts[e];
  int p0 = off + (jt << 6);
  int valid = min(64, cnt - (jt << 6));
  int o0 = blockIdx.x << 8;
  int t = threadIdx.x;
  if (t < 64) toks[t] = bucket[p0 + min(t, valid - 1)];
  const float* bbase = lb + ((size_t)e * NO + o0) * NR;
  #pragma unroll
  for (int kk = 0; kk < 4; ++kk) {
    int idx = (kk << 8) + t;
    int o = idx >> 2, rq = (idx & 3) << 2;
    float4 v = *(const float4*)(bbase + o * NR + rq);
    bt[rq + 0][o] = v.x; bt[rq + 1][o] = v.y; bt[rq + 2][o] = v.z; bt[rq + 3][o] = v.w;
  }
  { int tok = t >> 2, rq = (t & 3) << 2;
    float4 v = *(const float4*)(h + (size_t)(p0 + min(tok, valid - 1)) * NR + rq);
    ht[rq + 0][tok] = v.x; ht[rq + 1][tok] = v.y; ht[rq + 2][tok] = v.z; ht[rq + 3][tok] = v.w; }
  __syncthreads();
  int og = t & 31, tokg = t >> 5;
  int ob = og << 2, tb = tokg << 3;
  float4 z = make_float4(0.f,0.f,0.f,0.f);
  float4 aL0=z,aL1=z,aL2=z,aL3=z,aL4=z,aL5=z,aL6=z,aL7=z;
  float4 aH0=z,aH1=z,aH2=z,aH3=z,aH4=z,aH5=z,aH6=z,aH7=z;
  #pragma unroll
  for (int r = 0; r < 16; ++r) {
    float4 blo = *(const float4*)&bt[r][ob];
    float4 bhi = *(const float4*)&bt[r][ob + 128];
    float4 h0  = *(const float4*)&ht[r][tb];
    float4 h1  = *(const float4*)&ht[r][tb + 4];
    FMA4(aL0, h0.x, blo); FMA4(aH0, h0.x, bhi);
    FMA4(aL1, h0.y, blo); FMA4(aH1, h0.y, bhi);
    FMA4(aL2, h0.z, blo); FMA4(aH2, h0.z, bhi);
    FMA4(aL3, h0.w, blo); FMA4(aH3, h0.w, bhi);
    FMA4(aL4, h1.x, blo); FMA4(aH4, h1.x, bhi);
    FMA4(aL5, h1.y, blo); FMA4(aH5, h1.y, bhi);
    FMA4(aL6, h1.z, blo); FMA4(aH6, h1.z, bhi);
    FMA4(aL7, h1.w, blo); FMA4(aH7, h1.w, bhi);
  }
  #define ST(J, AL, AH) { int tt = tb + (J); if (tt < valid) { \
      float* p = out + (size_t)toks[tt] * NO + o0 + ob; \
      *(float4*)p = AL; *(float4*)(p + 128) = AH; } }
  ST(0, aL0, aH0); ST(1, aL1, aH1); ST(2, aL2, aH2); ST(3, aL3, aH3);
  ST(4, aL4, aH4); ST(5, aL5, aH5); ST(6, aL6, aH6); ST(7, aL7, aH7);
  #undef ST
}

// ---------------------------------------------------------------------------
extern "C" void kernel_launch(void* const* d_in, const int* in_sizes, int n_in,
                              void* d_out, int out_size, void* d_ws, size_t ws_size,
                              hipStream_t stream) {
  const float* x  = (const float*)d_in[0];
  const float* wg = (const float*)d_in[1];
  const float* wn = (const float*)d_in[2];
  const float* la = (const float*)d_in[3];
  const float* lb = (const float*)d_in[4];
  const float* nz = (const float*)d_in[5];
  float* out = (float*)d_out;

  char* ws = (char*)d_ws;
  float* h        = (float*)(ws);                 // 8192*16*4 = 524288 B
  int*   eid      = (int*)  (ws + 524288);        // 32768 B
  int*   bucket   = (int*)  (ws + 557056);        // 32768 B
  float* partials = (float*)(ws + 589824);        // 512*16*4 = 32768 B
  int*   counts   = (int*)  (ws + 622592);        // 32 B
  int*   fill     = (int*)  (ws + 622624);        // 32 B
  float* wT       = (float*)(ws + 622656);        // 16*1024*4 = 65536 B

  kT<<<16, 256, 0, stream>>>(wg, wn, wT);
  kA<<<512, 256, 0, stream>>>(x, wT, nz, eid, partials);
  kB<<<1, 256, 0, stream>>>(partials, out + OUT_ELEMS, counts, fill);
  kC<<<32, 256, 0, stream>>>(eid, counts, fill, bucket);
  kD<<<519, 256, 0, stream>>>(x, la, counts, bucket, h);
  kE<<<dim3(12, 135), 256, 0, stream>>>(h, lb, counts, bucket, out);
}